// Round 16
// baseline (22633.313 us; speedup 1.0000x reference)
//
#include <hip/hip_runtime.h>
#include <math.h>

typedef unsigned int u32;

#define T_SEQ   2048
#define NWG     256

// ---------------- workspace layout (bytes) ----------------
#define OFF_HBUF   0            // float[2][32][512] = 131072
#define OFF_CNT    131072       // u32[4][64] (4 counters, 256B apart) = 1024 (2048 resv)
#define OFF_LASTH  133120       // float[32][512] = 65536
#define WS_NEED    198656ull

// ---------------- fallback (round-2 proven) layout ----------------
#define FB_OFF_HBUF   0
#define FB_OFF_ARRIVE 131072
#define FB_OFF_LASTH  131328

__device__ __forceinline__ float sigm(float x) { return 1.0f / (1.0f + expf(-x)); }

// ---- LLC-coherent accessors (sc0 sc1 = bypass L1 + XCD L2); r8/r10-proven ----
__device__ __forceinline__ float4 ldg4s(const float* p) {
  float4 v;
  asm volatile("global_load_dwordx4 %0, %1, off sc0 sc1" : "=v"(v) : "v"(p) : "memory");
  return v;
}
__device__ __forceinline__ void stg1fs(float* p, float v) {
  asm volatile("global_store_dword %0, %1, off sc0 sc1" :: "v"(p), "v"(v) : "memory");
}

// =====================================================================
// Sequential LSTM v12: 256 WGs x 512 threads, 1 WG/CU (8 waves = 2/SIMD,
// VGPR cap 256 -> no spill pressure). r15 lesson: W-in-LDS at this lane
// map is structurally >=8-way bank-conflicted (1.6e9 measured); r13
// lesson: scalar W-in-regs + lane=k strided LDS reads = 0 conflicts.
// This round combines r13's conflict-free compute shape with r10/r15's
// proven 64-producer sync groups and 2-wave/SIMD TLP.
// ug = bid>>2 owns 8 units -> 32 gate rows; bg = bid&3 owns 8 batches.
// Wave wv owns rows wv*4..+4 (global R = (r>>3)*512 + ug*8 + (r&7)).
// LANE = K: thread k-cols = {lane + 64j, j<8} per 512-wide phase.
//   W/thread = 32rows*1024 / 512thr = 64 f32 VGPRs (r13-proven: 108 tot).
//   acc[4][8] = 32 regs.
// Operands staged per step into natural El/Hl[8][512] (coalesced f4
// stage writes; scalar lane-strided reads = bank lane%32, 2/bank FREE).
// Reduction: 6x shfl_xor over all 64 lanes + statically-predicated
// gsc writes (r13-proven). Sync: ONE monotone counter per bg (256B
// apart), 64 posts/step, target 64t (r10-proven). h via sc0sc1 +
// vmcnt(0) drain before post. Watchdog -> sticky dead (no hang).
// =====================================================================
__global__ void __launch_bounds__(512, 1)
lstm_seq(const int* __restrict__ x, const int* __restrict__ attn,
         const float* __restrict__ emb,
         const float* __restrict__ Wih, const float* __restrict__ Whh,
         const float* __restrict__ bih, const float* __restrict__ bhh,
         float* __restrict__ hbuf, u32* __restrict__ counters,
         float* __restrict__ lasth)
{
  __shared__ __align__(16) float El[8 * 512];
  __shared__ __align__(16) float Hl[8 * 512];
  __shared__ float gsc[256];
  __shared__ int s_dead;

  const int tid = threadIdx.x, bid = blockIdx.x;
  const int ug = bid >> 2, bg = bid & 3;
  const int wv = tid >> 6, lane = tid & 63;

  u32* cnt = counters + bg * 64;       // 256B-padded per-bg counter

  // ---- W -> registers (once): 4 rows x 8 scalars x 2 phases = 64 regs ----
  float wE[4][8], wH[4][8];
#pragma unroll
  for (int i = 0; i < 4; ++i) {
    int r = wv * 4 + i;                              // row 0..31
    int R = ((r >> 3) << 9) + ug * 8 + (r & 7);      // gate*512 + unit
    const float* pE = Wih + (size_t)R * 512 + lane;
    const float* pH = Whh + (size_t)R * 512 + lane;
#pragma unroll
    for (int j = 0; j < 8; ++j) { wE[i][j] = pE[64 * j]; wH[i][j] = pH[64 * j]; }
  }

  // ---- lengths (partials in El scratch as [64 chunks][8 b]) ----
  {
    int b = tid & 7, c = tid >> 3;     // c in [0,64)
    const int4* ap = (const int4*)(attn + (size_t)(bg * 8 + b) * 2048 + c * 32);
    int s = 0;
#pragma unroll
    for (int k = 0; k < 8; ++k) { int4 a = ap[k]; s += a.x + a.y + a.z + a.w; }
    El[c * 8 + b] = (float)s;
  }
  if (tid == 0) s_dead = 0;
  __syncthreads();
  int len = 0; float c_reg = 0.f;
  float bI = 0, bF = 0, bG = 0, bO = 0;
  if (tid < 64) {
    int b = tid & 7, uu = tid >> 3;    // unit 0..7
    int s = 0;
#pragma unroll
    for (int c = 0; c < 64; ++c) s += (int)El[c * 8 + b];
    len = s - 1; if (len < 0) len = T_SEQ - 1;
    int gu = ug * 8 + uu;
    bI = bih[gu]        + bhh[gu];
    bF = bih[512 + gu]  + bhh[512 + gu];
    bG = bih[1024 + gu] + bhh[1024 + gu];
    bO = bih[1536 + gu] + bhh[1536 + gu];
  }
  __syncthreads();   // El scratch done

  // staging geometry: thread stages chunks (b0, c0) and (b0+4, c0)
  const int b0 = tid >> 7;             // 0..3
  const int c0 = tid & 127;            // float4 column
  bool dead = false;

  for (int t = 0; t < T_SEQ; ++t) {
    // ---- emb stage: 2 coalesced f4/thread -> natural El ----
    {
      int xr0 = x[(size_t)(bg * 8 + b0) * 2048 + t];
      int xr1 = x[(size_t)(bg * 8 + b0 + 4) * 2048 + t];
      float4 e0 = *(const float4*)(emb + (size_t)xr0 * 512 + c0 * 4);
      float4 e1 = *(const float4*)(emb + (size_t)xr1 * 512 + c0 * 4);
      *(float4*)&El[(b0 * 128 + c0) * 4] = e0;
      *(float4*)&El[((b0 + 4) * 128 + c0) * 4] = e1;
    }
    __syncthreads();

    float acc[4][8];
#pragma unroll
    for (int i = 0; i < 4; ++i)
#pragma unroll
      for (int b = 0; b < 8; ++b) acc[i][b] = 0.f;

    // ---- emb FMA: scalar lane-strided (bank = lane%32, 2/bank = free) ----
#pragma unroll 2
    for (int b = 0; b < 8; ++b) {
      const float* ep = El + b * 512 + lane;
#pragma unroll
      for (int j = 0; j < 8; ++j) {
        float e = ep[64 * j];
        acc[0][b] += wE[0][j] * e;
        acc[1][b] += wE[1][j] * e;
        acc[2][b] += wE[2][j] * e;
        acc[3][b] += wE[3][j] * e;
      }
    }

    // ---- barrier: tid 0 polls the bg counter (r10-proven) ----
    if (tid == 0 && !dead) {
      int it = 0;
      const u32 target = (u32)(t << 6);              // 64 posts per step
      while (__hip_atomic_load(cnt, __ATOMIC_RELAXED, __HIP_MEMORY_SCOPE_AGENT) < target) {
        if (++it > (1 << 16)) { s_dead = 1; break; } // watchdog: no hang
        __builtin_amdgcn_s_sleep(4);
      }
    }
    __syncthreads();
    if (s_dead) dead = true;

    // ---- h stage: 2 coalesced sc0sc1 f4/thread -> natural Hl ----
    {
      const float* hsrc = hbuf + (((t + 1) & 1) << 14) + (size_t)(bg * 8) * 512;
      float4 h0 = ldg4s(hsrc + (size_t)(b0 * 128 + c0) * 4);
      float4 h1 = ldg4s(hsrc + (size_t)((b0 + 4) * 128 + c0) * 4);
      asm volatile("s_waitcnt vmcnt(0)" ::: "memory");
      __builtin_amdgcn_sched_barrier(0);
      *(float4*)&Hl[(b0 * 128 + c0) * 4] = h0;
      *(float4*)&Hl[((b0 + 4) * 128 + c0) * 4] = h1;
    }
    __syncthreads();

    // ---- h FMA ----
#pragma unroll 2
    for (int b = 0; b < 8; ++b) {
      const float* hp = Hl + b * 512 + lane;
#pragma unroll
      for (int j = 0; j < 8; ++j) {
        float e = hp[64 * j];
        acc[0][b] += wH[0][j] * e;
        acc[1][b] += wH[1][j] * e;
        acc[2][b] += wH[2][j] * e;
        acc[3][b] += wH[3][j] * e;
      }
    }

    // ---- k-reduction: full 64-lane xor tree ----
#pragma unroll
    for (int i = 0; i < 4; ++i)
#pragma unroll
      for (int b = 0; b < 8; ++b) {
        float v = acc[i][b];
        v += __shfl_xor(v, 1, 64);
        v += __shfl_xor(v, 2, 64);
        v += __shfl_xor(v, 4, 64);
        v += __shfl_xor(v, 8, 64);
        v += __shfl_xor(v, 16, 64);
        v += __shfl_xor(v, 32, 64);
        acc[i][b] = v;
      }
    // statically-predicated publish: lane i*8+b -> gsc[row][b]
#pragma unroll
    for (int i = 0; i < 4; ++i)
#pragma unroll
      for (int b = 0; b < 8; ++b)
        if (lane == i * 8 + b)
          gsc[(wv * 4 + i) * 8 + b] = acc[i][b];
    __syncthreads();

    // ---- activations + sc0sc1 h post (wave0 lanes), counter post ----
    if (tid < 64) {
      int b = tid & 7, uu = tid >> 3;
      float gi = gsc[(0  + uu) * 8 + b] + bI;      // rows: gate*8+uu
      float gf = gsc[(8  + uu) * 8 + b] + bF;
      float gg = gsc[(16 + uu) * 8 + b] + bG;
      float go = gsc[(24 + uu) * 8 + b] + bO;
      float iv = sigm(gi), fv = sigm(gf), ov = sigm(go), gv = tanhf(gg);
      c_reg = fv * c_reg + iv * gv;
      float hval = ov * tanhf(c_reg);
      int bglob = bg * 8 + b, unit = ug * 8 + uu;
      float* hd = hbuf + ((t & 1) << 14) + (bglob << 9) + unit;
      stg1fs(hd, hval);
      if (t == len) lasth[(bglob << 9) + unit] = hval;
      asm volatile("s_waitcnt vmcnt(0)" ::: "memory");   // wave0 stores at LLC
      if (tid == 0)
        __hip_atomic_fetch_add(cnt, 1u, __ATOMIC_RELAXED, __HIP_MEMORY_SCOPE_AGENT);
    }
  }
}

// =====================================================================
// FC head
// =====================================================================
__global__ void __launch_bounds__(128)
fc_kernel(const float* __restrict__ lasth, const float* __restrict__ fcW,
          const float* __restrict__ fcb, float* __restrict__ out)
{
  int tid = threadIdx.x;
  int b = tid >> 2, n = tid & 3;
  const float4* h4 = (const float4*)(lasth + (size_t)b * 512);
  const float4* w4 = (const float4*)(fcW + (size_t)n * 512);
  float s0 = 0.f, s1 = 0.f, s2 = 0.f, s3 = 0.f;
#pragma unroll 8
  for (int k = 0; k < 128; ++k) {
    float4 a = h4[k], c = w4[k];
    s0 += a.x * c.x; s1 += a.y * c.y; s2 += a.z * c.z; s3 += a.w * c.w;
  }
  out[b * 4 + n] = fcb[n] + ((s0 + s1) + (s2 + s3));
}

// =====================================================================
// Fallback: round-2 proven persistent kernel (only if ws too small)
// =====================================================================
__device__ __forceinline__ void gl2lds16(const void* gsrc, void* ldst) {
  __builtin_amdgcn_global_load_lds(
      (const __attribute__((address_space(1))) u32*)gsrc,
      (__attribute__((address_space(3))) u32*)ldst, 16, 0, 0);
}

__global__ void __launch_bounds__(256)
lstm_persist(const int* __restrict__ xidx, const int* __restrict__ attn,
             const float* __restrict__ emb,
             const float* __restrict__ Wih, const float* __restrict__ Whh,
             const float* __restrict__ bih, const float* __restrict__ bhh,
             float* __restrict__ hbuf, float* __restrict__ lasth,
             u32* __restrict__ arrive)
{
  __shared__ __align__(16) float Wl[8][1024];
  __shared__ __align__(16) float ul[2][32][64];
  __shared__ float gsc[32][8];

  const int tid  = threadIdx.x;
  const int wg   = blockIdx.x;
  const int lane = tid & 63;
  const int wv   = tid >> 6;
  const int r    = tid & 7;
  const int bb   = tid >> 3;
  const int brl  = bb & 7;

#pragma unroll 2
  for (int i = 0; i < 8; ++i) {
    int ci = i * 256 + tid;
    int rr = ci >> 8;
    int cc = ci & 255;
    int R  = ((rr >> 1) << 9) + (wg * 2 + (rr & 1));
    const float* src = (cc < 128) ? (Wih + (size_t)R * 512 + cc * 4)
                                  : (Whh + (size_t)R * 512 + (cc - 128) * 4);
    float4 v = *(const float4*)src;
    int slot = cc ^ (rr & 7);
    *(float4*)&Wl[rr][slot * 4] = v;
  }
  float bias;
  {
    int R = ((r >> 1) << 9) + (wg * 2 + (r & 1));
    bias = bih[R] + bhh[R];
  }
  {
    int pb = tid >> 3, pc = tid & 7;
    const int4* ap = (const int4*)(attn + pb * 2048 + pc * 256);
    int s = 0;
#pragma unroll 8
    for (int k = 0; k < 64; ++k) { int4 a = ap[k]; s += a.x + a.y + a.z + a.w; }
    gsc[pb][pc] = (float)s;
  }
  __syncthreads();
  int   len_reg = 0;
  float c_reg   = 0.f;
  if (tid < 64) {
    int b2 = tid & 31;
    int s = 0;
#pragma unroll
    for (int k = 0; k < 8; ++k) s += (int)gsc[b2][k];
    len_reg = s - 1;
    if (len_reg < 0) len_reg = 2047;
  }
  __syncthreads();

  const int idx_b = 8 * wv + (lane & 7);
  int idx_cur = xidx[(size_t)idx_b * 2048];

  for (int t = 0; t < T_SEQ; ++t) {
    int idx_next = (t < T_SEQ - 1) ? xidx[(size_t)idx_b * 2048 + t + 1] : 0;
    float a0 = bias, a1 = 0.f, a2 = 0.f, a3 = 0.f;
    const float* hsrc = hbuf + (((t + 1) & 1) << 14);

    auto stageE = [&](int jt, int buf) {
#pragma unroll
      for (int q = 0; q < 2; ++q) {
        int rlq = 4 * q + (lane >> 4);
        int sc = lane & 15;
        int kc = sc ^ (rlq & 7);
        int rowg = __shfl(idx_cur, rlq, 64);
        const float* g = emb + (size_t)rowg * 512 + jt * 64 + kc * 4;
        gl2lds16(g, (void*)&ul[buf][8 * wv + 4 * q][0]);
      }
    };
    auto stageH = [&](int jt, int buf) {
#pragma unroll
      for (int q = 0; q < 2; ++q) {
        int rlq = 4 * q + (lane >> 4);
        int sc = lane & 15;
        int kc = sc ^ (rlq & 7);
        int blq = 8 * wv + rlq;
        const float* g = hsrc + (size_t)blq * 512 + jt * 64 + kc * 4;
        gl2lds16(g, (void*)&ul[buf][8 * wv + 4 * q][0]);
      }
    };
    auto computeT = [&](int jg, int buf) {
#pragma unroll
      for (int kc = 0; kc < 16; ++kc) {
        float4 uv4 = *(const float4*)&ul[buf][bb][(kc ^ brl) * 4];
        float4 wv4 = *(const float4*)&Wl[r][(((jg << 4) + kc) ^ r) * 4];
        a0 += uv4.x * wv4.x; a1 += uv4.y * wv4.y;
        a2 += uv4.z * wv4.z; a3 += uv4.w * wv4.w;
      }
    };

    stageE(0, 0);
#pragma unroll
    for (int jt = 0; jt < 8; ++jt) {
      if (jt < 7) { stageE(jt + 1, (jt + 1) & 1); asm volatile("s_waitcnt vmcnt(2)" ::: "memory"); }
      else       { asm volatile("s_waitcnt vmcnt(0)" ::: "memory"); }
      computeT(jt, jt & 1);
    }

    if (tid == 0) {
      u32 target = (u32)t << 8;
      while (__hip_atomic_load(arrive, __ATOMIC_RELAXED, __HIP_MEMORY_SCOPE_AGENT) < target)
        __builtin_amdgcn_s_sleep(2);
    }
    __syncthreads();
    __builtin_amdgcn_fence(__ATOMIC_ACQUIRE, "agent");

    stageH(0, 0);
#pragma unroll
    for (int jt = 0; jt < 8; ++jt) {
      if (jt < 7) { stageH(jt + 1, (jt + 1) & 1); asm volatile("s_waitcnt vmcnt(2)" ::: "memory"); }
      else       { asm volatile("s_waitcnt vmcnt(0)" ::: "memory"); }
      computeT(8 + jt, jt & 1);
    }

    gsc[bb][r] = a0 + a1 + a2 + a3;
    __syncthreads();
    if (tid < 64) {
      int u  = tid >> 5;
      int b2 = tid & 31;
      float gi = gsc[b2][u];
      float gf = gsc[b2][2 + u];
      float gg = gsc[b2][4 + u];
      float go = gsc[b2][6 + u];
      float iv = sigm(gi), fv = sigm(gf), ov = sigm(go);
      float gv = tanhf(gg);
      c_reg = fv * c_reg + iv * gv;
      float hv = ov * tanhf(c_reg);
      int unit = (wg << 1) + u;
      hbuf[((t & 1) << 14) + (b2 << 9) + unit] = hv;
      if (t == len_reg) lasth[(b2 << 9) + unit] = hv;
      __builtin_amdgcn_fence(__ATOMIC_RELEASE, "agent");
      if (tid == 0)
        __hip_atomic_fetch_add(arrive, 1u, __ATOMIC_RELAXED, __HIP_MEMORY_SCOPE_AGENT);
    }
    idx_cur = idx_next;
  }
}

extern "C" void kernel_launch(void* const* d_in, const int* in_sizes, int n_in,
                              void* d_out, int out_size, void* d_ws, size_t ws_size,
                              hipStream_t stream) {
  const int*   x    = (const int*)d_in[0];
  const int*   attn = (const int*)d_in[1];
  const float* emb  = (const float*)d_in[2];
  const float* Wih  = (const float*)d_in[3];
  const float* Whh  = (const float*)d_in[4];
  const float* bih  = (const float*)d_in[5];
  const float* bhh  = (const float*)d_in[6];
  const float* fcW  = (const float*)d_in[7];
  const float* fcb  = (const float*)d_in[8];
  float* out = (float*)d_out;
  char* ws = (char*)d_ws;

  if (ws_size >= WS_NEED) {
    float* hbuf  = (float*)(ws + OFF_HBUF);
    u32*   cnts  = (u32*)(ws + OFF_CNT);
    float* lasth = (float*)(ws + OFF_LASTH);

    (void)hipMemsetAsync(ws, 0, OFF_LASTH, stream);   // hbuf + counters

    hipLaunchKernelGGL(lstm_seq, dim3(NWG), dim3(512), 0, stream,
                       x, attn, emb, Wih, Whh, bih, bhh, hbuf, cnts, lasth);
    hipLaunchKernelGGL(fc_kernel, dim3(1), dim3(128), 0, stream,
                       lasth, fcW, fcb, out);
  } else {
    float* hbuf   = (float*)(ws + FB_OFF_HBUF);
    u32*   arrive = (u32*)(ws + FB_OFF_ARRIVE);
    float* lasth  = (float*)(ws + FB_OFF_LASTH);
    (void)hipMemsetAsync(ws, 0, 131072 + 256, stream);
    hipLaunchKernelGGL(lstm_persist, dim3(256), dim3(256), 0, stream,
                       x, attn, emb, Wih, Whh, bih, bhh, hbuf, lasth, arrive);
    hipLaunchKernelGGL(fc_kernel, dim3(1), dim3(128), 0, stream,
                       lasth, fcW, fcb, out);
  }
}